// Round 1
// baseline (358.053 us; speedup 1.0000x reference)
//
#include <hip/hip_runtime.h>

// Problem constants: B=32, H=24, N=500, F_IN=64, F_OUT=4, M=16, O=H*N=12000
#define Bc   32
#define Oc   12000
#define Mc   16

// R2: LDS-free restructure.
//
// R1's LDS staging was the bottleneck: 320 ds_read_b128/thread = 1.31 MB LDS
// reads per block (~5x the VALU demand; VALUBusy 15%, HBM 24%, occupancy 18%,
// LDS 41KB also capped residency at 3 blocks/CU).
//
// New shape: block = 256 threads = 16 o x 16 b-groups, each thread register-
// blocks TWO b's (b = bg and bg+16). Weight reuse now lives in registers (2x)
// and in the global-load coalescer: the 4 lanes {oi, oi+16, oi+32, oi+48} of a
// wave read the SAME weight address -> merged into one L1 access. Each weight
// byte is fetched once per block, blocks own disjoint o's -> sigma_w/mu_w
// stream from HBM exactly once. No LDS, no barrier, no staging.
//
// Accumulators: 2 b x (mu[4] + sigma[4][4]) = 40 floats/thread.
// __launch_bounds__(256,3) floors occupancy at 3 blocks/CU -> all 750 blocks
// (2.93/CU) co-resident in a single round.
__global__ __launch_bounds__(256, 3) void mgr_fused_kernel(
    const float* __restrict__ x,        // [B, O, 64]
    const float* __restrict__ mu_w,     // [O, 64, 4]
    const float* __restrict__ mu_b,     // [O, 4]
    const float* __restrict__ sigma_w,  // [O, 64, 16]
    const float* __restrict__ sigma_b,  // [O, 16]
    const float* __restrict__ eps,      // [M, B, O, 4]
    float* __restrict__ out)            // [M, B, O, 4]
{
    const int tid = threadIdx.x;
    const int oi  = tid & 15;           // o fast in lane index -> coalesced eps/out
    const int bg  = tid >> 4;           // 0..15
    const int o   = blockIdx.x * 16 + oi;
    const int b0  = bg;
    const int b1  = bg + 16;

    const float4* __restrict__ muw4 = reinterpret_cast<const float4*>(mu_w) + o * 64;
    const float4* __restrict__ sw4  = reinterpret_cast<const float4*>(sigma_w) + o * 256;
    const float4* __restrict__ x40  = reinterpret_cast<const float4*>(x) + (b0 * Oc + o) * 16;
    const float4* __restrict__ x41  = reinterpret_cast<const float4*>(x) + (b1 * Oc + o) * 16;

    // biases -> accumulator init (tiny, L2-served, 4-lane broadcast)
    float4 amu0 = reinterpret_cast<const float4*>(mu_b)[o];
    float4 amu1 = amu0;
    float4 a00 = reinterpret_cast<const float4*>(sigma_b)[o * 4 + 0]; float4 a10 = a00;
    float4 a01 = reinterpret_cast<const float4*>(sigma_b)[o * 4 + 1]; float4 a11 = a01;
    float4 a02 = reinterpret_cast<const float4*>(sigma_b)[o * 4 + 2]; float4 a12 = a02;
    float4 a03 = reinterpret_cast<const float4*>(sigma_b)[o * 4 + 3]; float4 a13 = a03;

    // ---- main GEMM loop: 64 f, 5 weight float4 per f feed 40 FMAs ----
    #pragma unroll 4
    for (int fo = 0; fo < 16; ++fo) {
        const float4 xq0 = x40[fo];
        const float4 xq1 = x41[fo];
        #pragma unroll
        for (int fi = 0; fi < 4; ++fi) {
            const int f = 4 * fo + fi;
            const float xs0 = (fi == 0) ? xq0.x : (fi == 1) ? xq0.y : (fi == 2) ? xq0.z : xq0.w;
            const float xs1 = (fi == 0) ? xq1.x : (fi == 1) ? xq1.y : (fi == 2) ? xq1.z : xq1.w;

            float4 w = muw4[f];
            amu0.x = fmaf(xs0, w.x, amu0.x); amu0.y = fmaf(xs0, w.y, amu0.y);
            amu0.z = fmaf(xs0, w.z, amu0.z); amu0.w = fmaf(xs0, w.w, amu0.w);
            amu1.x = fmaf(xs1, w.x, amu1.x); amu1.y = fmaf(xs1, w.y, amu1.y);
            amu1.z = fmaf(xs1, w.z, amu1.z); amu1.w = fmaf(xs1, w.w, amu1.w);

            float4 s;
            s = sw4[4 * f + 0];
            a00.x = fmaf(xs0, s.x, a00.x); a00.y = fmaf(xs0, s.y, a00.y);
            a00.z = fmaf(xs0, s.z, a00.z); a00.w = fmaf(xs0, s.w, a00.w);
            a10.x = fmaf(xs1, s.x, a10.x); a10.y = fmaf(xs1, s.y, a10.y);
            a10.z = fmaf(xs1, s.z, a10.z); a10.w = fmaf(xs1, s.w, a10.w);
            s = sw4[4 * f + 1];
            a01.x = fmaf(xs0, s.x, a01.x); a01.y = fmaf(xs0, s.y, a01.y);
            a01.z = fmaf(xs0, s.z, a01.z); a01.w = fmaf(xs0, s.w, a01.w);
            a11.x = fmaf(xs1, s.x, a11.x); a11.y = fmaf(xs1, s.y, a11.y);
            a11.z = fmaf(xs1, s.z, a11.z); a11.w = fmaf(xs1, s.w, a11.w);
            s = sw4[4 * f + 2];
            a02.x = fmaf(xs0, s.x, a02.x); a02.y = fmaf(xs0, s.y, a02.y);
            a02.z = fmaf(xs0, s.z, a02.z); a02.w = fmaf(xs0, s.w, a02.w);
            a12.x = fmaf(xs1, s.x, a12.x); a12.y = fmaf(xs1, s.y, a12.y);
            a12.z = fmaf(xs1, s.z, a12.z); a12.w = fmaf(xs1, s.w, a12.w);
            s = sw4[4 * f + 3];
            a03.x = fmaf(xs0, s.x, a03.x); a03.y = fmaf(xs0, s.y, a03.y);
            a03.z = fmaf(xs0, s.z, a03.z); a03.w = fmaf(xs0, s.w, a03.w);
            a13.x = fmaf(xs1, s.x, a13.x); a13.y = fmaf(xs1, s.y, a13.y);
            a13.z = fmaf(xs1, s.z, a13.z); a13.w = fmaf(xs1, s.w, a13.w);
        }
    }

    // ---- epilogue: stream eps, write out (o fast dim -> 256B segments/wave) ----
    const float4* __restrict__ eps4 = reinterpret_cast<const float4*>(eps);
    float4* __restrict__ out4 = reinterpret_cast<float4*>(out);

    #pragma unroll 4
    for (int m = 0; m < Mc; ++m) {
        const int i0 = (m * Bc + b0) * Oc + o;
        const int i1 = (m * Bc + b1) * Oc + o;
        const float4 e0 = eps4[i0];
        const float4 e1 = eps4[i1];
        float4 r0, r1;
        r0.x = amu0.x + a00.x * e0.x + a00.y * e0.y + a00.z * e0.z + a00.w * e0.w;
        r0.y = amu0.y + a01.x * e0.x + a01.y * e0.y + a01.z * e0.z + a01.w * e0.w;
        r0.z = amu0.z + a02.x * e0.x + a02.y * e0.y + a02.z * e0.z + a02.w * e0.w;
        r0.w = amu0.w + a03.x * e0.x + a03.y * e0.y + a03.z * e0.z + a03.w * e0.w;
        r1.x = amu1.x + a10.x * e1.x + a10.y * e1.y + a10.z * e1.z + a10.w * e1.w;
        r1.y = amu1.y + a11.x * e1.x + a11.y * e1.y + a11.z * e1.z + a11.w * e1.w;
        r1.z = amu1.z + a12.x * e1.x + a12.y * e1.y + a12.z * e1.z + a12.w * e1.w;
        r1.w = amu1.w + a13.x * e1.x + a13.y * e1.y + a13.z * e1.z + a13.w * e1.w;
        out4[i0] = r0;
        out4[i1] = r1;
    }
}

extern "C" void kernel_launch(void* const* d_in, const int* in_sizes, int n_in,
                              void* d_out, int out_size, void* d_ws, size_t ws_size,
                              hipStream_t stream) {
    const float* x       = (const float*)d_in[0];
    const float* mu_w    = (const float*)d_in[1];
    const float* mu_b    = (const float*)d_in[2];
    const float* sigma_w = (const float*)d_in[3];
    const float* sigma_b = (const float*)d_in[4];
    const float* eps     = (const float*)d_in[5];
    float* out = (float*)d_out;

    dim3 grid(Oc / 16);  // 750 blocks, 16 o's each, all co-resident at 3 blocks/CU
    dim3 block(256);
    mgr_fused_kernel<<<grid, block, 0, stream>>>(x, mu_w, mu_b, sigma_w, sigma_b, eps, out);
}